// Round 7
// baseline (1027.290 us; speedup 1.0000x reference)
//
#include <hip/hip_runtime.h>
#include <hip/hip_bf16.h>
#include <math.h>

// ---------- types / helpers ----------
typedef short    short8  __attribute__((ext_vector_type(8)));
typedef float    floatx4 __attribute__((ext_vector_type(4)));

__device__ __forceinline__ float b2f(unsigned short u) {
    union { float f; unsigned int i; } v; v.i = ((unsigned int)u) << 16; return v.f;
}
__device__ __forceinline__ unsigned short f2b(float f) {
    union { float f; unsigned int i; } v; v.f = f;
    unsigned int b = v.i;
    return (unsigned short)((b + 0x7FFFu + ((b >> 16) & 1u)) >> 16);
}
// dual-dtype read: element i of input tensor that is bf16 (flag=0) or f32 (flag=1)
__device__ __forceinline__ float rd(const void* p, long i, int f) {
    return f ? ((const float*)p)[i] : b2f(((const unsigned short*)p)[i]);
}
// fast GELU via identity 0.5x(1+tanh u) = x / (1 + exp(-2u)), u = 0.79788x(1+0.044715x^2)
__device__ __forceinline__ float fgelu(float x) {
    float x2 = x * x;
    float t = x * fmaf(x2, -0.0713548163f, -1.5957691216f);   // t = -2u
    return __fdividef(x, 1.f + __expf(t));
}
// bijective XCD-chunk swizzle (m204): consecutive new-ids stay on one XCD's L2
__device__ __forceinline__ int xcd_swz(int bid, int nwg) {
    int q = nwg >> 3, r = nwg & 7;
    int xcd = bid & 7, loc = bid >> 3;
    return ((xcd < r) ? xcd * (q + 1) : r * (q + 1) + (xcd - r) * q) + loc;
}

#define NTOK_ 50176   // 16*56*56

// ---------- dtype detector ----------
__global__ __launch_bounds__(256) void k_detect(const unsigned short* __restrict__ x,
                                                int* __restrict__ flag) {
    __shared__ int cnt;
    if (threadIdx.x == 0) cnt = 0;
    __syncthreads();
    unsigned short v = x[threadIdx.x];
    int e = (v >> 7) & 0xFF;
    if (e >= 0x90) atomicAdd(&cnt, 1);
    __syncthreads();
    if (threadIdx.x == 0) *flag = (cnt >= 8) ? 1 : 0;
}

// ---------- xm = x + spe -> fp32 (+ optional bf16 mirror for layer-0 qkv) ----------
__global__ __launch_bounds__(256) void k_add_spe(const void* __restrict__ x,
                                                 const void* __restrict__ spe,
                                                 float* __restrict__ xm,
                                                 unsigned short* __restrict__ xb,
                                                 const int* __restrict__ flagp) {
    const int f = *flagp;
    long i = ((long)blockIdx.x * 256 + threadIdx.x) * 4;
    float4 o;
    if (f) {
        float4 a = *(const float4*)((const float*)x + i);
        float4 b = *(const float4*)((const float*)spe + i);
        o.x = a.x + b.x; o.y = a.y + b.y; o.z = a.z + b.z; o.w = a.w + b.w;
    } else {
        ushort4 a = *(const ushort4*)((const unsigned short*)x + i);
        ushort4 b = *(const ushort4*)((const unsigned short*)spe + i);
        o.x = b2f(a.x) + b2f(b.x); o.y = b2f(a.y) + b2f(b.y);
        o.z = b2f(a.z) + b2f(b.z); o.w = b2f(a.w) + b2f(b.w);
    }
    *(float4*)(xm + i) = o;
    if (xb) {
        ushort4 h; h.x = f2b(o.x); h.y = f2b(o.y); h.z = f2b(o.z); h.w = f2b(o.w);
        *(ushort4*)(xb + i) = h;
    }
}

// ---------- tiled weight transpose: (K,N) -> (N,K) bf16, coalesced both sides ----------
__global__ __launch_bounds__(256) void k_transpose(const void* __restrict__ in, long ioff,
                                                   unsigned short* __restrict__ out,
                                                   int K, int N,
                                                   const int* __restrict__ flagp) {
    __shared__ unsigned short tile[32][33];
    const int f = *flagp;
    int n0 = blockIdx.x * 32, k0 = blockIdx.y * 32;
    int tx = threadIdx.x & 31, ty = threadIdx.x >> 5;   // 32 x 8
#pragma unroll
    for (int i = 0; i < 4; i++) {
        int k = k0 + ty + i * 8;
        long idx = ioff + (long)k * N + n0 + tx;
        unsigned short v = f ? f2b(((const float*)in)[idx])
                             : ((const unsigned short*)in)[idx];   // bit-exact passthrough
        tile[ty + i * 8][tx] = v;
    }
    __syncthreads();
#pragma unroll
    for (int i = 0; i < 4; i++) {
        int n = n0 + ty + i * 8;
        out[(long)n * K + k0 + tx] = tile[tx][ty + i * 8];
    }
}

// ---------- CPB table ----------
__global__ __launch_bounds__(512) void k_cpb(const void* __restrict__ cw1,
                                             const void* __restrict__ cb1,
                                             const void* __restrict__ cw2,
                                             const void* __restrict__ cb2,
                                             float* __restrict__ cpb,
                                             const int* __restrict__ flagp) {
    const int f = *flagp;
    int p = blockIdx.x;      // pair index i*49+j
    int l = blockIdx.y;      // layer
    int t = threadIdx.x;     // 0..511
    int i = p / 49, j = p - i * 49;
    int yi = i / 7, xi = i - yi * 7, yj = j / 7, xj = j - yj * 7;
    float dy = (float)(yj - yi), dx = (float)(xj - xi);
    float sy = (dy > 0.f) ? 1.f : ((dy < 0.f) ? -1.f : 0.f);
    float sx = (dx > 0.f) ? 1.f : ((dx < 0.f) ? -1.f : 0.f);
    float r0 = sy * log1pf(fabsf(dy));
    float r1 = sx * log1pf(fabsf(dx));
    float h = r0 * rd(cw1, l * 1024 + t, f) + r1 * rd(cw1, l * 1024 + 512 + t, f)
            + rd(cb1, l * 512 + t, f);
    h = fmaxf(h, 0.f);
    __shared__ float red[512];
    for (int hh = 0; hh < 8; hh++) {
        red[t] = h * rd(cw2, (long)(l * 512 + t) * 8 + hh, f);
        __syncthreads();
        for (int s = 256; s > 0; s >>= 1) {
            if (t < s) red[t] += red[t + s];
            __syncthreads();
        }
        if (t == 0) cpb[((long)l * 8 + hh) * 2401 + p] = red[0] + rd(cb2, l * 8 + hh, f);
        __syncthreads();
    }
}

// ---------- cast (+roll) fp32 xm(group) -> bf16 xb(group)  (G>1 fallback path) ----------
__global__ __launch_bounds__(256) void k_cast_roll(const float* __restrict__ xmg,
                                                   unsigned short* __restrict__ xb, int shift) {
    int gid = blockIdx.x * 256 + threadIdx.x;       // Mg*64 threads
    int c4 = (gid & 63) * 4;
    int t = gid >> 6;
    int x = t % 56; int t2 = t / 56;
    int y = t2 % 56;
    int b = t2 / 56;                                 // local batch in group
    int ys = y + shift; if (ys >= 56) ys -= 56;
    int xs = x + shift; if (xs >= 56) xs -= 56;
    float4 v = *(const float4*)(xmg + (((long)b * 3136 + ys * 56 + xs) * 256 + c4));
    ushort4 o; o.x = f2b(v.x); o.y = f2b(v.y); o.z = f2b(v.z); o.w = f2b(v.w);
    *(ushort4*)(xb + ((long)t * 256 + c4)) = o;
}

// ---------- MFMA GEMM: C[M,N] = A[M,K] @ Bt[N,K]^T (+bias)(+gelu), bf16 out ----------
// flags: 1=bias, 2=gelu
// Round-7: B fragments read DIRECTLY from global (L2-resident panel; each lane's
// 16B short8 is exactly the fragment the LDS path produced -> bit-identical).
// One-step register rotate on both A-staging regs and B frags: the ds_write stores
// last iteration's data (zero vmcnt wait in loop); bf L2 latency hides under MFMAs.
// r5/r6 evidence: gemm_ln flat at ~92us across occupancy 16->32% => the per-step
// B LDS round trip (write+barrier+read + 12M conflict cycles) was the invariant cost.
__global__ __launch_bounds__(256) void gemm_bt(const unsigned short* __restrict__ A,
                                               const unsigned short* __restrict__ Bt,
                                               const void* __restrict__ bias, long boff,
                                               void* __restrict__ Cp,
                                               int M, int N, int K, int flags,
                                               const int* __restrict__ flagp) {
    __shared__ __align__(16) unsigned short smem[16896];   // As (first 10240B) / epilogue T (33792B)
    unsigned short* As = smem;            // 128 x 40
    const int f = *flagp;
    const int tid = threadIdx.x;
    const int lane = tid & 63;
    const int wave = tid >> 6;
    const int wrow = (wave >> 1) * 64;
    const int wcol = (wave & 1) * 64;

    const int nwg = gridDim.x * gridDim.y;
    const int nb = xcd_swz(blockIdx.y * gridDim.x + blockIdx.x, nwg);
    const int bn = nb % gridDim.x, bm = nb / gridDim.x;   // bn fast within an XCD chunk

    floatx4 acc[4][4] = {};

    const int arow = tid >> 2;       // 0..63
    const int aseg = (tid & 3) * 8;  // 0,8,16,24
    const unsigned short* Ag = A + (long)(bm * 128 + arow) * K + aseg;
    const long rstep = (long)64 * K;

    const int q = lane >> 4;        // quad 0..3
    const int mrow = lane & 15;

    // B row base pointers: direct L2 fragment reads (panel shared by all bm-blocks)
    const unsigned short* Brow[4];
#pragma unroll
    for (int nt = 0; nt < 4; nt++)
        Brow[nt] = Bt + (long)(bn * 128 + wcol + nt * 16 + mrow) * K + q * 8;

    uint4 a_cur0 = *(const uint4*)(Ag);
    uint4 a_cur1 = *(const uint4*)(Ag + rstep);
    short8 bf_cur[4], bf_nxt[4];
#pragma unroll
    for (int nt = 0; nt < 4; nt++) bf_cur[nt] = *(const short8*)(Brow[nt]);

    for (int k0 = 0; k0 < K; k0 += 32) {
        const int kn = k0 + 32;
        uint4 a_nxt0, a_nxt1;
        if (kn < K) {
            a_nxt0 = *(const uint4*)(Ag + kn);
            a_nxt1 = *(const uint4*)(Ag + kn + rstep);
#pragma unroll
            for (int nt = 0; nt < 4; nt++) bf_nxt[nt] = *(const short8*)(Brow[nt] + kn);
        }
        __syncthreads();                     // waves done reading As from prev step
        *(uint4*)(As + arow * 40 + aseg) = a_cur0;       // data loaded last iter: no wait
        *(uint4*)(As + (arow + 64) * 40 + aseg) = a_cur1;
        __syncthreads();

        short8 af_[4];
#pragma unroll
        for (int mt = 0; mt < 4; mt++)
            af_[mt] = *(const short8*)(As + (wrow + mt * 16 + mrow) * 40 + q * 8);
#pragma unroll
        for (int mt = 0; mt < 4; mt++)
#pragma unroll
            for (int nt = 0; nt < 4; nt++)
                acc[mt][nt] = __builtin_amdgcn_mfma_f32_16x16x32_bf16(af_[mt], bf_cur[nt], acc[mt][nt], 0, 0, 0);
        if (kn < K) {
            a_cur0 = a_nxt0; a_cur1 = a_nxt1;
#pragma unroll
            for (int nt = 0; nt < 4; nt++) bf_cur[nt] = bf_nxt[nt];
        }
    }

    __syncthreads();   // K-loop LDS reads complete before epilogue reuse

    // ---- bf16 output: stage full 128x128 tile at once (row pad -> 132) ----
    unsigned short* T = smem;
#pragma unroll
    for (int nt = 0; nt < 4; nt++) {
        int col = wcol + nt * 16 + mrow;
        float bv = (flags & 1) ? rd(bias, boff + bn * 128 + col, f) : 0.f;
#pragma unroll
        for (int mt = 0; mt < 4; mt++) {
            int row0 = wrow + mt * 16 + q * 4;
#pragma unroll
            for (int r = 0; r < 4; r++) {
                float v = acc[mt][nt][r] + bv;
                if (flags & 2) v = fgelu(v);
                T[(row0 + r) * 132 + col] = f2b(v);
            }
        }
    }
    __syncthreads();
    unsigned short* Cu = (unsigned short*)Cp;
    int row = tid >> 4;              // 0..15
    int col8 = (tid & 15) * 8;
#pragma unroll
    for (int p = 0; p < 8; p++) {
        int rr = p * 16 + row;
        *(uint4*)(Cu + (long)(bm * 128 + rr) * N + bn * 128 + col8) =
            *(const uint4*)(T + rr * 132 + col8);
    }
}

// ---------- fused GEMM(N=256) + PostNorm-LN + residual ----------
// xbmode: 0 = no xb write, 1 = xb at same token, 2 = xb rolled back by 3 (feeds next
// layer's shifted qkv; removes the separate cast_roll pass when G==1).
// Round-7: B direct-from-L2 with register rotate (see gemm_bt header); A keeps
// the coalesced LDS path with its staging register rotated one step ahead.
__global__ __launch_bounds__(256) void gemm_ln(const unsigned short* __restrict__ A,
                                               const unsigned short* __restrict__ Bt,
                                               const void* __restrict__ bias, long boff,
                                               const void* __restrict__ g, long goff,
                                               const void* __restrict__ bb, long b2off,
                                               float* __restrict__ xm,
                                               unsigned short* __restrict__ xb,
                                               int K, int xbmode,
                                               const int* __restrict__ flagp) {
    __shared__ __align__(16) unsigned short smem[17152];   // As (2560B) / Tf (34304B)
    __shared__ float pp[4][32][2];
    unsigned short* As = smem;            // 32 x 40
    const int f = *flagp;
    const int tid = threadIdx.x;
    const int lane = tid & 63;
    const int wv = tid >> 6;
    const int wcol = wv * 64;
    const int bm = blockIdx.x;

    floatx4 acc[2][4] = {};
    const int brow = tid >> 2;       // A stage row for tid<128
    const int bseg = (tid & 3) * 8;
    const unsigned short* Ag = A + (long)(bm * 32 + brow) * K + bseg;   // deref only if tid<128
    const int q = lane >> 4;
    const int c = lane & 15;

    // B row base pointers: direct L2 fragment reads (weight panel shared by ALL blocks)
    const unsigned short* Brow[4];
#pragma unroll
    for (int nt = 0; nt < 4; nt++)
        Brow[nt] = Bt + (long)(wcol + nt * 16 + c) * K + q * 8;

    uint4 a_cur;
    if (tid < 128) a_cur = *(const uint4*)(Ag);
    short8 bf_cur[4], bf_nxt[4];
#pragma unroll
    for (int nt = 0; nt < 4; nt++) bf_cur[nt] = *(const short8*)(Brow[nt]);

    for (int k0 = 0; k0 < K; k0 += 32) {
        const int kn = k0 + 32;
        uint4 a_nxt;
        if (kn < K) {
            if (tid < 128) a_nxt = *(const uint4*)(Ag + kn);
#pragma unroll
            for (int nt = 0; nt < 4; nt++) bf_nxt[nt] = *(const short8*)(Brow[nt] + kn);
        }
        __syncthreads();
        if (tid < 128) *(uint4*)(As + brow * 40 + bseg) = a_cur;   // no wait: loaded last iter
        __syncthreads();

        short8 af_[2];
#pragma unroll
        for (int mt = 0; mt < 2; mt++)
            af_[mt] = *(const short8*)(As + (mt * 16 + c) * 40 + q * 8);
#pragma unroll
        for (int mt = 0; mt < 2; mt++)
#pragma unroll
            for (int nt = 0; nt < 4; nt++)
                acc[mt][nt] = __builtin_amdgcn_mfma_f32_16x16x32_bf16(af_[mt], bf_cur[nt], acc[mt][nt], 0, 0, 0);
        if (kn < K) {
            if (tid < 128) a_cur = a_nxt;
#pragma unroll
            for (int nt = 0; nt < 4; nt++) bf_cur[nt] = bf_nxt[nt];
        }
    }
    __syncthreads();   // K-loop LDS reads complete before Tf reuse

    // ---- per-row sum / sumsq (bias included), cross-wave via pp ----
    float bv[4];
#pragma unroll
    for (int nt = 0; nt < 4; nt++)
        bv[nt] = rd(bias, boff + wcol + nt * 16 + c, f);
#pragma unroll
    for (int mt = 0; mt < 2; mt++) {
#pragma unroll
        for (int r = 0; r < 4; r++) {
            float s1 = 0.f, s2 = 0.f;
#pragma unroll
            for (int nt = 0; nt < 4; nt++) {
                float v = acc[mt][nt][r] + bv[nt];
                s1 += v; s2 += v * v;
            }
            s1 += __shfl_xor(s1, 1); s2 += __shfl_xor(s2, 1);
            s1 += __shfl_xor(s1, 2); s2 += __shfl_xor(s2, 2);
            s1 += __shfl_xor(s1, 4); s2 += __shfl_xor(s2, 4);
            s1 += __shfl_xor(s1, 8); s2 += __shfl_xor(s2, 8);
            if (c == 0) {
                pp[wv][mt * 16 + q * 4 + r][0] = s1;
                pp[wv][mt * 16 + q * 4 + r][1] = s2;
            }
        }
    }

    // ---- preload LN params for this lane's 4 columns ----
    const int c0 = lane * 4;
    float4 gv, bbv;
    gv.x = rd(g, goff + c0 + 0, f); gv.y = rd(g, goff + c0 + 1, f);
    gv.z = rd(g, goff + c0 + 2, f); gv.w = rd(g, goff + c0 + 3, f);
    bbv.x = rd(bb, b2off + c0 + 0, f); bbv.y = rd(bb, b2off + c0 + 1, f);
    bbv.z = rd(bb, b2off + c0 + 2, f); bbv.w = rd(bb, b2off + c0 + 3, f);

    // ---- one-shot fp32 restage (32 x 268) + wave-per-row coalesced LN apply ----
    float* Tf = (float*)smem;      // 32 x 268 fp32 = 34304 B (fits smem exactly)
#pragma unroll
    for (int mt = 0; mt < 2; mt++)
#pragma unroll
        for (int nt = 0; nt < 4; nt++)
#pragma unroll
            for (int r = 0; r < 4; r++)
                Tf[(mt * 16 + q * 4 + r) * 268 + wcol + nt * 16 + c] = acc[mt][nt][r] + bv[nt];
    __syncthreads();   // covers both Tf and pp writes
#pragma unroll
    for (int it = 0; it < 8; it++) {
        int row = wv * 8 + it;           // 0..31, this wave owns 8 rows
        float sum = pp[0][row][0] + pp[1][row][0] + pp[2][row][0] + pp[3][row][0];
        float ssq = pp[0][row][1] + pp[1][row][1] + pp[2][row][1] + pp[3][row][1];
        float mean = sum * (1.f / 256.f);
        float var = ssq * (1.f / 256.f) - mean * mean;
        float rstd = rsqrtf(fmaxf(var, 0.f) + 1e-5f);
        long tok = (long)(bm * 32 + row);
        long grow = tok * 256;
        float4 t = *(const float4*)(Tf + row * 268 + c0);
        float4 xv = *(const float4*)(xm + grow + c0);
        float4 o;
        o.x = (t.x - mean) * rstd * gv.x + bbv.x + xv.x;
        o.y = (t.y - mean) * rstd * gv.y + bbv.y + xv.y;
        o.z = (t.z - mean) * rstd * gv.z + bbv.z + xv.z;
        o.w = (t.w - mean) * rstd * gv.w + bbv.w + xv.w;
        *(float4*)(xm + grow + c0) = o;
        if (xbmode) {
            long xg = grow;
            if (xbmode == 2) {
                int bi = (int)(tok / 3136); int r2 = (int)(tok - (long)bi * 3136);
                int y = r2 / 56; int x = r2 - y * 56;
                y = (y >= 3) ? y - 3 : y + 53;
                x = (x >= 3) ? x - 3 : x + 53;
                xg = ((long)bi * 3136 + y * 56 + x) * 256;
            }
            ushort4 hb; hb.x = f2b(o.x); hb.y = f2b(o.y); hb.z = f2b(o.z); hb.w = f2b(o.w);
            *(ushort4*)(xb + xg + c0) = hb;
        }
    }
}

// ---------- MFMA window attention: one wave per (head, window, batch) ----------
__global__ __launch_bounds__(256) void k_attn(const unsigned short* __restrict__ qkv, // (NB,56,56,768) bf16
                                              const float* __restrict__ cpb,          // [8][2401] this layer
                                              const void* __restrict__ tau, long toff,
                                              unsigned short* __restrict__ out,       // (NB,56,56,256) un-rolled
                                              int shifted,
                                              const int* __restrict__ flagp) {
    __shared__ __align__(16) unsigned short Pbuf[4][64 * 72];  // P, A-layout staging
    __shared__ __align__(16) unsigned short Vt[4][32 * 72];    // V^T, B-layout staging
    __shared__ float inq_s[4][64], ink_s[4][64];

    const int f = *flagp;
    const int tid = threadIdx.x;
    const int wv = tid >> 6;
    const int lane = tid & 63;
    const int h = blockIdx.x * 4 + wv;
    const int w = blockIdx.y, b = blockIdx.z;
    const int wy = w >> 3, wx = w & 7;
    const int q = lane >> 4;      // quad
    const int c = lane & 15;      // tile row (A/B frag) / tile col (C frag)

    // ---- load Q/K fragments from global + accumulate row square-sums ----
    short8 qa[4], kb[4];
    float sqv[4], skv[4];
#pragma unroll
    for (int mt = 0; mt < 4; mt++) {
        int i = mt * 16 + c; if (i > 48) i = 48;
        int py = i / 7, px = i - py * 7;
        long base = (((long)b * 56 + wy * 7 + py) * 56 + wx * 7 + px) * 768 + h * 32 + q * 8;
        qa[mt] = *(const short8*)(qkv + base);
        kb[mt] = *(const short8*)(qkv + base + 256);
        float sq = 0.f, sk = 0.f;
#pragma unroll
        for (int e = 0; e < 8; e++) {
            float a = b2f((unsigned short)qa[mt][e]); sq += a * a;
            float k2 = b2f((unsigned short)kb[mt][e]); sk += k2 * k2;
        }
        sqv[mt] = sq; skv[mt] = sk;
    }
#pragma unroll
    for (int mt = 0; mt < 4; mt++) {
        float sq = sqv[mt]; sq += __shfl_xor(sq, 16); sq += __shfl_xor(sq, 32);
        float sk = skv[mt]; sk += __shfl_xor(sk, 16); sk += __shfl_xor(sk, 32);
        if (q == 0) {
            inq_s[wv][mt * 16 + c] = 1.f / fmaxf(sqrtf(sq), 1e-12f);
            ink_s[wv][mt * 16 + c] = 1.f / fmaxf(sqrtf(sk), 1e-12f);
        }
    }

    // ---- S = Q K^T (64x64 padded) ----
    floatx4 acc[4][4] = {};
#pragma unroll
    for (int mt = 0; mt < 4; mt++)
#pragma unroll
        for (int nt = 0; nt < 4; nt++)
            acc[mt][nt] = __builtin_amdgcn_mfma_f32_16x16x32_bf16(qa[mt], kb[nt], acc[mt][nt], 0, 0, 0);

    // ---- stage V^T into LDS (zero pad cols first) ----
#pragma unroll
    for (int z = lane; z < 576; z += 64)
        *(uint2*)(&Vt[wv][z * 4]) = make_uint2(0u, 0u);
    if (lane < 49) {
        int py = lane / 7, px = lane - py * 7;
        long base = (((long)b * 56 + wy * 7 + py) * 56 + wx * 7 + px) * 768 + h * 32 + 512;
#pragma unroll
        for (int dd = 0; dd < 32; dd += 8) {
            ushort4 v0 = *(const ushort4*)(qkv + base + dd);
            ushort4 v1 = *(const ushort4*)(qkv + base + dd + 4);
            Vt[wv][(dd + 0) * 72 + lane] = v0.x;
            Vt[wv][(dd + 1) * 72 + lane] = v0.y;
            Vt[wv][(dd + 2) * 72 + lane] = v0.z;
            Vt[wv][(dd + 3) * 72 + lane] = v0.w;
            Vt[wv][(dd + 4) * 72 + lane] = v1.x;
            Vt[wv][(dd + 5) * 72 + lane] = v1.y;
            Vt[wv][(dd + 6) * 72 + lane] = v1.z;
            Vt[wv][(dd + 7) * 72 + lane] = v1.w;
        }
    }

    // ---- scale + cpb + mask + softmax (registers + 16-lane shuffles) -> P in LDS ----
    float scale = 1.f / fmaxf(rd(tau, toff + h, f), 0.01f);
#pragma unroll
    for (int mt = 0; mt < 4; mt++) {
#pragma unroll
        for (int r = 0; r < 4; r++) {
            int i = mt * 16 + q * 4 + r;
            int ci = (i < 49) ? i : 48;
            int pyi = ci / 7, pxi = ci - pyi * 7;
            float qi = inq_s[wv][ci] * scale;
            float vals[4];
#pragma unroll
            for (int nt = 0; nt < 4; nt++) {
                int j = nt * 16 + c;
                if (j < 49) {
                    float v = acc[mt][nt][r] * qi * ink_s[wv][j]
                            + cpb[h * 2401 + ci * 49 + j];
                    if (shifted) {
                        int pyj = j / 7, pxj = j - pyj * 7;
                        if (wy == 7 && ((pyi >= 4) != (pyj >= 4))) v = -1e30f;
                        if (wx == 7 && ((pxi >= 4) != (pxj >= 4))) v = -1e30f;
                    }
                    vals[nt] = v;
                } else vals[nt] = -1e30f;
            }
            float m = fmaxf(fmaxf(vals[0], vals[1]), fmaxf(vals[2], vals[3]));
            m = fmaxf(m, __shfl_xor(m, 1)); m = fmaxf(m, __shfl_xor(m, 2));
            m = fmaxf(m, __shfl_xor(m, 4)); m = fmaxf(m, __shfl_xor(m, 8));
            float s = 0.f;
#pragma unroll
            for (int nt = 0; nt < 4; nt++) { vals[nt] = __expf(vals[nt] - m); s += vals[nt]; }
            s += __shfl_xor(s, 1); s += __shfl_xor(s, 2);
            s += __shfl_xor(s, 4); s += __shfl_xor(s, 8);
            float rinv = 1.f / s;
#pragma unroll
            for (int nt = 0; nt < 4; nt++)
                Pbuf[wv][i * 72 + nt * 16 + c] = f2b(vals[nt] * rinv);
        }
    }

    // ---- O = P V  (64x32, K=64 in 2 steps) ----
    floatx4 accO[4][2] = {};
#pragma unroll
    for (int ks = 0; ks < 2; ks++) {
        short8 pa[4], vb[2];
#pragma unroll
        for (int mt = 0; mt < 4; mt++)
            pa[mt] = *(const short8*)(&Pbuf[wv][(mt * 16 + c) * 72 + ks * 32 + q * 8]);
#pragma unroll
        for (int nt = 0; nt < 2; nt++)
            vb[nt] = *(const short8*)(&Vt[wv][(nt * 16 + c) * 72 + ks * 32 + q * 8]);
#pragma unroll
        for (int mt = 0; mt < 4; mt++)
#pragma unroll
            for (int nt = 0; nt < 2; nt++)
                accO[mt][nt] = __builtin_amdgcn_mfma_f32_16x16x32_bf16(pa[mt], vb[nt], accO[mt][nt], 0, 0, 0);
    }

    // ---- write O (un-roll fold) ----
    int sh = shifted ? 3 : 0;
#pragma unroll
    for (int mt = 0; mt < 4; mt++) {
#pragma unroll
        for (int r = 0; r < 4; r++) {
            int i = mt * 16 + q * 4 + r;
            if (i < 49) {
                int py = i / 7, px = i - py * 7;
                int yo = wy * 7 + py + sh; if (yo >= 56) yo -= 56;
                int xo = wx * 7 + px + sh; if (xo >= 56) xo -= 56;
                long ob = (((long)b * 56 + yo) * 56 + xo) * 256 + h * 32;
                out[ob + c]      = f2b(accO[mt][0][r]);
                out[ob + 16 + c] = f2b(accO[mt][1][r]);
            }
        }
    }
}

// ---------- final LN -> out (dtype per flag) ----------
__global__ __launch_bounds__(256) void k_final(const float* __restrict__ xm,
                                               const void* __restrict__ g,
                                               const void* __restrict__ bb,
                                               void* __restrict__ out,
                                               const int* __restrict__ flagp) {
    const int f = *flagp;
    int t = blockIdx.x, c = threadIdx.x;
    long off = (long)t * 256 + c;
    float v = xm[off];
    __shared__ float red[256];
    red[c] = v; __syncthreads();
#pragma unroll
    for (int s = 128; s > 0; s >>= 1) {
        if (c < s) red[c] += red[c + s];
        __syncthreads();
    }
    float mean = red[0] * (1.f / 256.f);
    __syncthreads();
    float d = v - mean;
    red[c] = d * d; __syncthreads();
#pragma unroll
    for (int s = 128; s > 0; s >>= 1) {
        if (c < s) red[c] += red[c + s];
        __syncthreads();
    }
    float var = red[0] * (1.f / 256.f);
    float ln = d * rsqrtf(var + 1e-5f) * rd(g, c, f) + rd(bb, c, f);
    if (f) ((float*)out)[off] = ln;
    else   ((unsigned short*)out)[off] = f2b(ln);
}

// ---------- launch ----------
extern "C" void kernel_launch(void* const* d_in, const int* in_sizes, int n_in,
                              void* d_out, int out_size, void* d_ws, size_t ws_size,
                              hipStream_t stream) {
    char* ws = (char*)d_ws;
    // fixed region
    float*          xm    = (float*)(ws + 0);                    // 51,380,224 B
    unsigned short* wt    = (unsigned short*)(ws + 51380224);    //  3,145,728 B
    float*          cpb   = (float*)(ws + 54525952);             //    153,664 B
    int*            flagp = (int*)(ws + 54679616);
    const size_t DYN = 54680576;

    // adaptive group count: batches are independent; pick largest Mg that fits ws
    long Mg = NTOK_; int G = 1;
    while (G <= 8) {
        Mg = NTOK_ / G;
        if (DYN + (size_t)Mg * 2560 <= ws_size) break;
        G <<= 1;
    }
    if (G > 8) { G = 8; Mg = NTOK_ / 8; }
    const int NB = 16 / G;
    const bool fused = (G == 1);   // single-group: fuse cast/roll into producer epilogues

    unsigned short* xb   = (unsigned short*)(ws + DYN);               // Mg*512 B
    unsigned short* qkvb = (unsigned short*)(ws + DYN + Mg * 512);    // Mg*1536 B
    unsigned short* hid  = (unsigned short*)(ws + DYN + Mg * 512);    // Mg*2048 B (alias qkvb)

    k_detect<<<1, 256, 0, stream>>>((const unsigned short*)d_in[0], flagp);

    for (int l = 0; l < 2; l++) {
        unsigned short* base = wt + (long)l * 786432;
        k_transpose<<<dim3(24, 8), 256, 0, stream>>>(d_in[2],  (long)l * 196608, base,          256, 768,  flagp);
        k_transpose<<<dim3(8, 8),  256, 0, stream>>>(d_in[8],  (long)l * 65536,  base + 196608, 256, 256,  flagp);
        k_transpose<<<dim3(32, 8), 256, 0, stream>>>(d_in[12], (long)l * 262144, base + 262144, 256, 1024, flagp);
        k_transpose<<<dim3(8, 32), 256, 0, stream>>>(d_in[14], (long)l * 262144, base + 524288, 1024, 256, flagp);
    }
    k_cpb<<<dim3(2401, 2), 512, 0, stream>>>(d_in[4], d_in[5], d_in[6], d_in[7], cpb, flagp);
    k_add_spe<<<dim3(12544), 256, 0, stream>>>(d_in[0], d_in[1], xm,
                                               fused ? xb : (unsigned short*)nullptr, flagp);

    for (int l = 0; l < 2; l++) {
        int sh = (l & 1) ? 3 : 0;
        unsigned short* base = wt + (long)l * 786432;
        for (int g = 0; g < G; g++) {
            long m0 = (long)g * Mg;
            if (!fused)
                k_cast_roll<<<dim3(Mg / 4), 256, 0, stream>>>(xm + m0 * 256, xb, sh);
            // qkv = xb @ qkv_w -> bf16   (bn fast + XCD chunk swizzle: A-panel stays on one L2)
            gemm_bt<<<dim3(6, Mg / 128), 256, 0, stream>>>(xb, base, nullptr, 0, qkvb,
                                                           (int)Mg, 768, 256, 4, flagp);
            k_attn<<<dim3(2, 64, NB), 256, 0, stream>>>(qkvb, cpb + (long)l * 19208,
                                                        d_in[3], (long)l * 8, xb, (l & 1), flagp);
            // proj + LN1 + residual (fused); xb refreshed unshifted for fc1
            gemm_ln<<<dim3(Mg / 32), 256, 0, stream>>>(xb, base + 196608, d_in[9], (long)l * 256,
                                                       d_in[10], (long)l * 256, d_in[11], (long)l * 256,
                                                       xm + m0 * 256, xb, 256, 1, flagp);
            // hidden = gelu(xb @ fw1 + fb1) -> bf16
            gemm_bt<<<dim3(8, Mg / 128), 256, 0, stream>>>(xb, base + 262144, d_in[13], (long)l * 1024,
                                                           hid, (int)Mg, 1024, 256, 1 | 2 | 4, flagp);
            // fw2 + LN2 + residual (fused); xb write: rolled for next layer (l=0),
            // skipped when dead (l=1, fused), unshifted in grouped fallback
            int xbm = fused ? ((l == 0) ? 2 : 0) : 1;
            gemm_ln<<<dim3(Mg / 32), 256, 0, stream>>>(hid, base + 524288, d_in[15], (long)l * 256,
                                                       d_in[16], (long)l * 256, d_in[17], (long)l * 256,
                                                       xm + m0 * 256, xb, 1024, xbm, flagp);
        }
    }
    k_final<<<dim3(NTOK_), 256, 0, stream>>>(xm, d_in[18], d_in[19], d_out, flagp);
}

// Round 8
// 905.982 us; speedup vs baseline: 1.1339x; 1.1339x over previous
//
#include <hip/hip_runtime.h>
#include <hip/hip_bf16.h>
#include <math.h>

// ---------- types / helpers ----------
typedef short    short8  __attribute__((ext_vector_type(8)));
typedef float    floatx4 __attribute__((ext_vector_type(4)));

__device__ __forceinline__ float b2f(unsigned short u) {
    union { float f; unsigned int i; } v; v.i = ((unsigned int)u) << 16; return v.f;
}
__device__ __forceinline__ unsigned short f2b(float f) {
    union { float f; unsigned int i; } v; v.f = f;
    unsigned int b = v.i;
    return (unsigned short)((b + 0x7FFFu + ((b >> 16) & 1u)) >> 16);
}
// dual-dtype read: element i of input tensor that is bf16 (flag=0) or f32 (flag=1)
__device__ __forceinline__ float rd(const void* p, long i, int f) {
    return f ? ((const float*)p)[i] : b2f(((const unsigned short*)p)[i]);
}
// fast GELU via identity 0.5x(1+tanh u) = x / (1 + exp(-2u)), u = 0.79788x(1+0.044715x^2)
__device__ __forceinline__ float fgelu(float x) {
    float x2 = x * x;
    float t = x * fmaf(x2, -0.0713548163f, -1.5957691216f);   // t = -2u
    return __fdividef(x, 1.f + __expf(t));
}
// bijective XCD-chunk swizzle (m204): consecutive new-ids stay on one XCD's L2
__device__ __forceinline__ int xcd_swz(int bid, int nwg) {
    int q = nwg >> 3, r = nwg & 7;
    int xcd = bid & 7, loc = bid >> 3;
    return ((xcd < r) ? xcd * (q + 1) : r * (q + 1) + (xcd - r) * q) + loc;
}

#define NTOK_ 50176   // 16*56*56

// ---------- dtype detector ----------
__global__ __launch_bounds__(256) void k_detect(const unsigned short* __restrict__ x,
                                                int* __restrict__ flag) {
    __shared__ int cnt;
    if (threadIdx.x == 0) cnt = 0;
    __syncthreads();
    unsigned short v = x[threadIdx.x];
    int e = (v >> 7) & 0xFF;
    if (e >= 0x90) atomicAdd(&cnt, 1);
    __syncthreads();
    if (threadIdx.x == 0) *flag = (cnt >= 8) ? 1 : 0;
}

// ---------- xm = x + spe -> fp32 (+ optional bf16 mirror for layer-0 qkv) ----------
__global__ __launch_bounds__(256) void k_add_spe(const void* __restrict__ x,
                                                 const void* __restrict__ spe,
                                                 float* __restrict__ xm,
                                                 unsigned short* __restrict__ xb,
                                                 const int* __restrict__ flagp) {
    const int f = *flagp;
    long i = ((long)blockIdx.x * 256 + threadIdx.x) * 4;
    float4 o;
    if (f) {
        float4 a = *(const float4*)((const float*)x + i);
        float4 b = *(const float4*)((const float*)spe + i);
        o.x = a.x + b.x; o.y = a.y + b.y; o.z = a.z + b.z; o.w = a.w + b.w;
    } else {
        ushort4 a = *(const ushort4*)((const unsigned short*)x + i);
        ushort4 b = *(const ushort4*)((const unsigned short*)spe + i);
        o.x = b2f(a.x) + b2f(b.x); o.y = b2f(a.y) + b2f(b.y);
        o.z = b2f(a.z) + b2f(b.z); o.w = b2f(a.w) + b2f(b.w);
    }
    *(float4*)(xm + i) = o;
    if (xb) {
        ushort4 h; h.x = f2b(o.x); h.y = f2b(o.y); h.z = f2b(o.z); h.w = f2b(o.w);
        *(ushort4*)(xb + i) = h;
    }
}

// ---------- tiled weight transpose: (K,N) -> (N,K) bf16, coalesced both sides ----------
__global__ __launch_bounds__(256) void k_transpose(const void* __restrict__ in, long ioff,
                                                   unsigned short* __restrict__ out,
                                                   int K, int N,
                                                   const int* __restrict__ flagp) {
    __shared__ unsigned short tile[32][33];
    const int f = *flagp;
    int n0 = blockIdx.x * 32, k0 = blockIdx.y * 32;
    int tx = threadIdx.x & 31, ty = threadIdx.x >> 5;   // 32 x 8
#pragma unroll
    for (int i = 0; i < 4; i++) {
        int k = k0 + ty + i * 8;
        long idx = ioff + (long)k * N + n0 + tx;
        unsigned short v = f ? f2b(((const float*)in)[idx])
                             : ((const unsigned short*)in)[idx];   // bit-exact passthrough
        tile[ty + i * 8][tx] = v;
    }
    __syncthreads();
#pragma unroll
    for (int i = 0; i < 4; i++) {
        int n = n0 + ty + i * 8;
        out[(long)n * K + k0 + tx] = tile[tx][ty + i * 8];
    }
}

// ---------- CPB table ----------
__global__ __launch_bounds__(512) void k_cpb(const void* __restrict__ cw1,
                                             const void* __restrict__ cb1,
                                             const void* __restrict__ cw2,
                                             const void* __restrict__ cb2,
                                             float* __restrict__ cpb,
                                             const int* __restrict__ flagp) {
    const int f = *flagp;
    int p = blockIdx.x;      // pair index i*49+j
    int l = blockIdx.y;      // layer
    int t = threadIdx.x;     // 0..511
    int i = p / 49, j = p - i * 49;
    int yi = i / 7, xi = i - yi * 7, yj = j / 7, xj = j - yj * 7;
    float dy = (float)(yj - yi), dx = (float)(xj - xi);
    float sy = (dy > 0.f) ? 1.f : ((dy < 0.f) ? -1.f : 0.f);
    float sx = (dx > 0.f) ? 1.f : ((dx < 0.f) ? -1.f : 0.f);
    float r0 = sy * log1pf(fabsf(dy));
    float r1 = sx * log1pf(fabsf(dx));
    float h = r0 * rd(cw1, l * 1024 + t, f) + r1 * rd(cw1, l * 1024 + 512 + t, f)
            + rd(cb1, l * 512 + t, f);
    h = fmaxf(h, 0.f);
    __shared__ float red[512];
    for (int hh = 0; hh < 8; hh++) {
        red[t] = h * rd(cw2, (long)(l * 512 + t) * 8 + hh, f);
        __syncthreads();
        for (int s = 256; s > 0; s >>= 1) {
            if (t < s) red[t] += red[t + s];
            __syncthreads();
        }
        if (t == 0) cpb[((long)l * 8 + hh) * 2401 + p] = red[0] + rd(cb2, l * 8 + hh, f);
        __syncthreads();
    }
}

// ---------- cast (+roll) fp32 xm(group) -> bf16 xb(group)  (G>1 fallback path) ----------
__global__ __launch_bounds__(256) void k_cast_roll(const float* __restrict__ xmg,
                                                   unsigned short* __restrict__ xb, int shift) {
    int gid = blockIdx.x * 256 + threadIdx.x;       // Mg*64 threads
    int c4 = (gid & 63) * 4;
    int t = gid >> 6;
    int x = t % 56; int t2 = t / 56;
    int y = t2 % 56;
    int b = t2 / 56;                                 // local batch in group
    int ys = y + shift; if (ys >= 56) ys -= 56;
    int xs = x + shift; if (xs >= 56) xs -= 56;
    float4 v = *(const float4*)(xmg + (((long)b * 3136 + ys * 56 + xs) * 256 + c4));
    ushort4 o; o.x = f2b(v.x); o.y = f2b(v.y); o.z = f2b(v.z); o.w = f2b(v.w);
    *(ushort4*)(xb + ((long)t * 256 + c4)) = o;
}

// ---------- MFMA GEMM: C[M,N] = A[M,K] @ Bt[N,K]^T (+bias)(+gelu), bf16 out ----------
// flags: 1=bias, 2=gelu
// r7 structure KEPT (aggregate r6->r7 delta attributes ~-13us/dispatch to this
// kernel): B fragments direct from L2 with one-step register rotate; A via LDS
// with staging regs rotated one step ahead (no vmcnt wait at the ds_write).
__global__ __launch_bounds__(256) void gemm_bt(const unsigned short* __restrict__ A,
                                               const unsigned short* __restrict__ Bt,
                                               const void* __restrict__ bias, long boff,
                                               void* __restrict__ Cp,
                                               int M, int N, int K, int flags,
                                               const int* __restrict__ flagp) {
    __shared__ __align__(16) unsigned short smem[16896];   // As (first 10240B) / epilogue T (33792B)
    unsigned short* As = smem;            // 128 x 40
    const int f = *flagp;
    const int tid = threadIdx.x;
    const int lane = tid & 63;
    const int wave = tid >> 6;
    const int wrow = (wave >> 1) * 64;
    const int wcol = (wave & 1) * 64;

    const int nwg = gridDim.x * gridDim.y;
    const int nb = xcd_swz(blockIdx.y * gridDim.x + blockIdx.x, nwg);
    const int bn = nb % gridDim.x, bm = nb / gridDim.x;   // bn fast within an XCD chunk

    floatx4 acc[4][4] = {};

    const int arow = tid >> 2;       // 0..63
    const int aseg = (tid & 3) * 8;  // 0,8,16,24
    const unsigned short* Ag = A + (long)(bm * 128 + arow) * K + aseg;
    const long rstep = (long)64 * K;

    const int q = lane >> 4;        // quad 0..3
    const int mrow = lane & 15;

    // B row base pointers: direct L2 fragment reads (panel shared by all bm-blocks)
    const unsigned short* Brow[4];
#pragma unroll
    for (int nt = 0; nt < 4; nt++)
        Brow[nt] = Bt + (long)(bn * 128 + wcol + nt * 16 + mrow) * K + q * 8;

    uint4 a_cur0 = *(const uint4*)(Ag);
    uint4 a_cur1 = *(const uint4*)(Ag + rstep);
    short8 bf_cur[4], bf_nxt[4];
#pragma unroll
    for (int nt = 0; nt < 4; nt++) bf_cur[nt] = *(const short8*)(Brow[nt]);

    for (int k0 = 0; k0 < K; k0 += 32) {
        const int kn = k0 + 32;
        uint4 a_nxt0, a_nxt1;
        if (kn < K) {
            a_nxt0 = *(const uint4*)(Ag + kn);
            a_nxt1 = *(const uint4*)(Ag + kn + rstep);
#pragma unroll
            for (int nt = 0; nt < 4; nt++) bf_nxt[nt] = *(const short8*)(Brow[nt] + kn);
        }
        __syncthreads();                     // waves done reading As from prev step
        *(uint4*)(As + arow * 40 + aseg) = a_cur0;       // data loaded last iter: no wait
        *(uint4*)(As + (arow + 64) * 40 + aseg) = a_cur1;
        __syncthreads();

        short8 af_[4];
#pragma unroll
        for (int mt = 0; mt < 4; mt++)
            af_[mt] = *(const short8*)(As + (wrow + mt * 16 + mrow) * 40 + q * 8);
#pragma unroll
        for (int mt = 0; mt < 4; mt++)
#pragma unroll
            for (int nt = 0; nt < 4; nt++)
                acc[mt][nt] = __builtin_amdgcn_mfma_f32_16x16x32_bf16(af_[mt], bf_cur[nt], acc[mt][nt], 0, 0, 0);
        if (kn < K) {
            a_cur0 = a_nxt0; a_cur1 = a_nxt1;
#pragma unroll
            for (int nt = 0; nt < 4; nt++) bf_cur[nt] = bf_nxt[nt];
        }
    }

    __syncthreads();   // K-loop LDS reads complete before epilogue reuse

    // ---- bf16 output: stage full 128x128 tile at once (row pad -> 132) ----
    unsigned short* T = smem;
#pragma unroll
    for (int nt = 0; nt < 4; nt++) {
        int col = wcol + nt * 16 + mrow;
        float bv = (flags & 1) ? rd(bias, boff + bn * 128 + col, f) : 0.f;
#pragma unroll
        for (int mt = 0; mt < 4; mt++) {
            int row0 = wrow + mt * 16 + q * 4;
#pragma unroll
            for (int r = 0; r < 4; r++) {
                float v = acc[mt][nt][r] + bv;
                if (flags & 2) v = fgelu(v);
                T[(row0 + r) * 132 + col] = f2b(v);
            }
        }
    }
    __syncthreads();
    unsigned short* Cu = (unsigned short*)Cp;
    int row = tid >> 4;              // 0..15
    int col8 = (tid & 15) * 8;
#pragma unroll
    for (int p = 0; p < 8; p++) {
        int rr = p * 16 + row;
        *(uint4*)(Cu + (long)(bm * 128 + rr) * N + bn * 128 + col8) =
            *(const uint4*)(T + rr * 132 + col8);
    }
}

// ---------- fused GEMM(N=256) + PostNorm-LN + residual ----------
// xbmode: 0 = no xb write, 1 = xb at same token, 2 = xb rolled back by 3 (feeds next
// layer's shifted qkv), 3 = FUSED FINAL LN: no xm/xb write; compute the network's
// final LayerNorm over the new xm row in-register (wave owns the full 256-col row)
// and write d_out directly. Removes the k_final dispatch + 103 MB of xm round-trip.
// K-loop: r6 LDS-staged B (r7's direct-B scatter cost +37us here -> reverted).
__global__ __launch_bounds__(256) void gemm_ln(const unsigned short* __restrict__ A,
                                               const unsigned short* __restrict__ Bt,
                                               const void* __restrict__ bias, long boff,
                                               const void* __restrict__ g, long goff,
                                               const void* __restrict__ bb, long b2off,
                                               float* __restrict__ xm,
                                               unsigned short* __restrict__ xb,
                                               int K, int xbmode,
                                               const void* __restrict__ fg,
                                               const void* __restrict__ fb,
                                               void* __restrict__ outp,
                                               const int* __restrict__ flagp) {
    __shared__ __align__(16) unsigned short smem[17152];   // 34304 B (staging / Tf)
    __shared__ float pp[4][32][2];
    unsigned short* As = smem;            // 32 x 40
    unsigned short* Bs = smem + 1280;     // 256 x 40
    const int f = *flagp;
    const int tid = threadIdx.x;
    const int lane = tid & 63;
    const int wv = tid >> 6;
    const int wcol = wv * 64;
    const int bm = blockIdx.x;

    floatx4 acc[2][4] = {};
    const int brow = tid >> 2;       // 0..63 (B stage row; A uses 0..31 from tid<128)
    const int bseg = (tid & 3) * 8;
    const unsigned short* Ag = A + (long)(bm * 32 + brow) * K + bseg;   // deref only if tid<128
    const unsigned short* Bg = Bt + (long)brow * K + bseg;
    const long brow2 = (long)64 * K;
    const int q = lane >> 4;
    const int c = lane & 15;

    for (int k0 = 0; k0 < K; k0 += 32) {
        uint4 a0;
        if (tid < 128) a0 = *(const uint4*)(Ag + k0);
        uint4 b0 = *(const uint4*)(Bg + k0);
        uint4 b1 = *(const uint4*)(Bg + k0 + brow2);
        uint4 b2 = *(const uint4*)(Bg + k0 + 2 * brow2);
        uint4 b3 = *(const uint4*)(Bg + k0 + 3 * brow2);
        __syncthreads();
        if (tid < 128) *(uint4*)(As + brow * 40 + bseg) = a0;
        *(uint4*)(Bs + brow * 40 + bseg) = b0;
        *(uint4*)(Bs + (brow + 64) * 40 + bseg) = b1;
        *(uint4*)(Bs + (brow + 128) * 40 + bseg) = b2;
        *(uint4*)(Bs + (brow + 192) * 40 + bseg) = b3;
        __syncthreads();

        short8 af_[2], bf_[4];
#pragma unroll
        for (int mt = 0; mt < 2; mt++)
            af_[mt] = *(const short8*)(As + (mt * 16 + c) * 40 + q * 8);
#pragma unroll
        for (int nt = 0; nt < 4; nt++)
            bf_[nt] = *(const short8*)(Bs + (wcol + nt * 16 + c) * 40 + q * 8);
#pragma unroll
        for (int mt = 0; mt < 2; mt++)
#pragma unroll
            for (int nt = 0; nt < 4; nt++)
                acc[mt][nt] = __builtin_amdgcn_mfma_f32_16x16x32_bf16(af_[mt], bf_[nt], acc[mt][nt], 0, 0, 0);
    }
    __syncthreads();   // K-loop LDS reads complete before Tf reuse

    // ---- per-row sum / sumsq (bias included), cross-wave via pp ----
    float bv[4];
#pragma unroll
    for (int nt = 0; nt < 4; nt++)
        bv[nt] = rd(bias, boff + wcol + nt * 16 + c, f);
#pragma unroll
    for (int mt = 0; mt < 2; mt++) {
#pragma unroll
        for (int r = 0; r < 4; r++) {
            float s1 = 0.f, s2 = 0.f;
#pragma unroll
            for (int nt = 0; nt < 4; nt++) {
                float v = acc[mt][nt][r] + bv[nt];
                s1 += v; s2 += v * v;
            }
            s1 += __shfl_xor(s1, 1); s2 += __shfl_xor(s2, 1);
            s1 += __shfl_xor(s1, 2); s2 += __shfl_xor(s2, 2);
            s1 += __shfl_xor(s1, 4); s2 += __shfl_xor(s2, 4);
            s1 += __shfl_xor(s1, 8); s2 += __shfl_xor(s2, 8);
            if (c == 0) {
                pp[wv][mt * 16 + q * 4 + r][0] = s1;
                pp[wv][mt * 16 + q * 4 + r][1] = s2;
            }
        }
    }

    // ---- preload LN params for this lane's 4 columns ----
    const int c0 = lane * 4;
    float4 gv, bbv, fgv, fbv;
    gv.x = rd(g, goff + c0 + 0, f); gv.y = rd(g, goff + c0 + 1, f);
    gv.z = rd(g, goff + c0 + 2, f); gv.w = rd(g, goff + c0 + 3, f);
    bbv.x = rd(bb, b2off + c0 + 0, f); bbv.y = rd(bb, b2off + c0 + 1, f);
    bbv.z = rd(bb, b2off + c0 + 2, f); bbv.w = rd(bb, b2off + c0 + 3, f);
    if (xbmode == 3) {
        fgv.x = rd(fg, c0 + 0, f); fgv.y = rd(fg, c0 + 1, f);
        fgv.z = rd(fg, c0 + 2, f); fgv.w = rd(fg, c0 + 3, f);
        fbv.x = rd(fb, c0 + 0, f); fbv.y = rd(fb, c0 + 1, f);
        fbv.z = rd(fb, c0 + 2, f); fbv.w = rd(fb, c0 + 3, f);
    }

    // ---- one-shot fp32 restage (32 x 268) + wave-per-row coalesced LN apply ----
    float* Tf = (float*)smem;      // 32 x 268 fp32 = 34304 B (fits smem exactly)
#pragma unroll
    for (int mt = 0; mt < 2; mt++)
#pragma unroll
        for (int nt = 0; nt < 4; nt++)
#pragma unroll
            for (int r = 0; r < 4; r++)
                Tf[(mt * 16 + q * 4 + r) * 268 + wcol + nt * 16 + c] = acc[mt][nt][r] + bv[nt];
    __syncthreads();   // covers both Tf and pp writes
#pragma unroll
    for (int it = 0; it < 8; it++) {
        int row = wv * 8 + it;           // 0..31, this wave owns 8 rows
        float sum = pp[0][row][0] + pp[1][row][0] + pp[2][row][0] + pp[3][row][0];
        float ssq = pp[0][row][1] + pp[1][row][1] + pp[2][row][1] + pp[3][row][1];
        float mean = sum * (1.f / 256.f);
        float var = ssq * (1.f / 256.f) - mean * mean;
        float rstd = rsqrtf(fmaxf(var, 0.f) + 1e-5f);
        long tok = (long)(bm * 32 + row);
        long grow = tok * 256;
        float4 t = *(const float4*)(Tf + row * 268 + c0);
        float4 xv = *(const float4*)(xm + grow + c0);
        float4 o;
        o.x = (t.x - mean) * rstd * gv.x + bbv.x + xv.x;
        o.y = (t.y - mean) * rstd * gv.y + bbv.y + xv.y;
        o.z = (t.z - mean) * rstd * gv.z + bbv.z + xv.z;
        o.w = (t.w - mean) * rstd * gv.w + bbv.w + xv.w;
        if (xbmode == 3) {
            // ---- fused final LN over this row (o = new xm, never materialized) ----
            float s1 = o.x + o.y + o.z + o.w;
            s1 += __shfl_xor(s1, 1); s1 += __shfl_xor(s1, 2);
            s1 += __shfl_xor(s1, 4); s1 += __shfl_xor(s1, 8);
            s1 += __shfl_xor(s1, 16); s1 += __shfl_xor(s1, 32);
            float fmean = s1 * (1.f / 256.f);
            float d0 = o.x - fmean, d1 = o.y - fmean, d2 = o.z - fmean, d3 = o.w - fmean;
            float s2 = d0 * d0 + d1 * d1 + d2 * d2 + d3 * d3;
            s2 += __shfl_xor(s2, 1); s2 += __shfl_xor(s2, 2);
            s2 += __shfl_xor(s2, 4); s2 += __shfl_xor(s2, 8);
            s2 += __shfl_xor(s2, 16); s2 += __shfl_xor(s2, 32);
            float frstd = rsqrtf(s2 * (1.f / 256.f) + 1e-5f);
            float r0 = d0 * frstd * fgv.x + fbv.x;
            float r1 = d1 * frstd * fgv.y + fbv.y;
            float r2 = d2 * frstd * fgv.z + fbv.z;
            float r3 = d3 * frstd * fgv.w + fbv.w;
            if (f) {
                float4 fo; fo.x = r0; fo.y = r1; fo.z = r2; fo.w = r3;
                *(float4*)((float*)outp + grow + c0) = fo;
            } else {
                ushort4 ho; ho.x = f2b(r0); ho.y = f2b(r1); ho.z = f2b(r2); ho.w = f2b(r3);
                *(ushort4*)((unsigned short*)outp + grow + c0) = ho;
            }
        } else {
            *(float4*)(xm + grow + c0) = o;
            if (xbmode) {
                long xg = grow;
                if (xbmode == 2) {
                    int bi = (int)(tok / 3136); int r2i = (int)(tok - (long)bi * 3136);
                    int y = r2i / 56; int x = r2i - y * 56;
                    y = (y >= 3) ? y - 3 : y + 53;
                    x = (x >= 3) ? x - 3 : x + 53;
                    xg = ((long)bi * 3136 + y * 56 + x) * 256;
                }
                ushort4 hb; hb.x = f2b(o.x); hb.y = f2b(o.y); hb.z = f2b(o.z); hb.w = f2b(o.w);
                *(ushort4*)(xb + xg + c0) = hb;
            }
        }
    }
}

// ---------- MFMA window attention: one wave per (head, window, batch) ----------
__global__ __launch_bounds__(256) void k_attn(const unsigned short* __restrict__ qkv, // (NB,56,56,768) bf16
                                              const float* __restrict__ cpb,          // [8][2401] this layer
                                              const void* __restrict__ tau, long toff,
                                              unsigned short* __restrict__ out,       // (NB,56,56,256) un-rolled
                                              int shifted,
                                              const int* __restrict__ flagp) {
    __shared__ __align__(16) unsigned short Pbuf[4][64 * 72];  // P, A-layout staging
    __shared__ __align__(16) unsigned short Vt[4][32 * 72];    // V^T, B-layout staging
    __shared__ float inq_s[4][64], ink_s[4][64];

    const int f = *flagp;
    const int tid = threadIdx.x;
    const int wv = tid >> 6;
    const int lane = tid & 63;
    const int h = blockIdx.x * 4 + wv;
    const int w = blockIdx.y, b = blockIdx.z;
    const int wy = w >> 3, wx = w & 7;
    const int q = lane >> 4;      // quad
    const int c = lane & 15;      // tile row (A/B frag) / tile col (C frag)

    // ---- load Q/K fragments from global + accumulate row square-sums ----
    short8 qa[4], kb[4];
    float sqv[4], skv[4];
#pragma unroll
    for (int mt = 0; mt < 4; mt++) {
        int i = mt * 16 + c; if (i > 48) i = 48;
        int py = i / 7, px = i - py * 7;
        long base = (((long)b * 56 + wy * 7 + py) * 56 + wx * 7 + px) * 768 + h * 32 + q * 8;
        qa[mt] = *(const short8*)(qkv + base);
        kb[mt] = *(const short8*)(qkv + base + 256);
        float sq = 0.f, sk = 0.f;
#pragma unroll
        for (int e = 0; e < 8; e++) {
            float a = b2f((unsigned short)qa[mt][e]); sq += a * a;
            float k2 = b2f((unsigned short)kb[mt][e]); sk += k2 * k2;
        }
        sqv[mt] = sq; skv[mt] = sk;
    }
#pragma unroll
    for (int mt = 0; mt < 4; mt++) {
        float sq = sqv[mt]; sq += __shfl_xor(sq, 16); sq += __shfl_xor(sq, 32);
        float sk = skv[mt]; sk += __shfl_xor(sk, 16); sk += __shfl_xor(sk, 32);
        if (q == 0) {
            inq_s[wv][mt * 16 + c] = 1.f / fmaxf(sqrtf(sq), 1e-12f);
            ink_s[wv][mt * 16 + c] = 1.f / fmaxf(sqrtf(sk), 1e-12f);
        }
    }

    // ---- S = Q K^T (64x64 padded) ----
    floatx4 acc[4][4] = {};
#pragma unroll
    for (int mt = 0; mt < 4; mt++)
#pragma unroll
        for (int nt = 0; nt < 4; nt++)
            acc[mt][nt] = __builtin_amdgcn_mfma_f32_16x16x32_bf16(qa[mt], kb[nt], acc[mt][nt], 0, 0, 0);

    // ---- stage V^T into LDS (zero pad cols first) ----
#pragma unroll
    for (int z = lane; z < 576; z += 64)
        *(uint2*)(&Vt[wv][z * 4]) = make_uint2(0u, 0u);
    if (lane < 49) {
        int py = lane / 7, px = lane - py * 7;
        long base = (((long)b * 56 + wy * 7 + py) * 56 + wx * 7 + px) * 768 + h * 32 + 512;
#pragma unroll
        for (int dd = 0; dd < 32; dd += 8) {
            ushort4 v0 = *(const ushort4*)(qkv + base + dd);
            ushort4 v1 = *(const ushort4*)(qkv + base + dd + 4);
            Vt[wv][(dd + 0) * 72 + lane] = v0.x;
            Vt[wv][(dd + 1) * 72 + lane] = v0.y;
            Vt[wv][(dd + 2) * 72 + lane] = v0.z;
            Vt[wv][(dd + 3) * 72 + lane] = v0.w;
            Vt[wv][(dd + 4) * 72 + lane] = v1.x;
            Vt[wv][(dd + 5) * 72 + lane] = v1.y;
            Vt[wv][(dd + 6) * 72 + lane] = v1.z;
            Vt[wv][(dd + 7) * 72 + lane] = v1.w;
        }
    }

    // ---- scale + cpb + mask + softmax (registers + 16-lane shuffles) -> P in LDS ----
    float scale = 1.f / fmaxf(rd(tau, toff + h, f), 0.01f);
#pragma unroll
    for (int mt = 0; mt < 4; mt++) {
#pragma unroll
        for (int r = 0; r < 4; r++) {
            int i = mt * 16 + q * 4 + r;
            int ci = (i < 49) ? i : 48;
            int pyi = ci / 7, pxi = ci - pyi * 7;
            float qi = inq_s[wv][ci] * scale;
            float vals[4];
#pragma unroll
            for (int nt = 0; nt < 4; nt++) {
                int j = nt * 16 + c;
                if (j < 49) {
                    float v = acc[mt][nt][r] * qi * ink_s[wv][j]
                            + cpb[h * 2401 + ci * 49 + j];
                    if (shifted) {
                        int pyj = j / 7, pxj = j - pyj * 7;
                        if (wy == 7 && ((pyi >= 4) != (pyj >= 4))) v = -1e30f;
                        if (wx == 7 && ((pxi >= 4) != (pxj >= 4))) v = -1e30f;
                    }
                    vals[nt] = v;
                } else vals[nt] = -1e30f;
            }
            float m = fmaxf(fmaxf(vals[0], vals[1]), fmaxf(vals[2], vals[3]));
            m = fmaxf(m, __shfl_xor(m, 1)); m = fmaxf(m, __shfl_xor(m, 2));
            m = fmaxf(m, __shfl_xor(m, 4)); m = fmaxf(m, __shfl_xor(m, 8));
            float s = 0.f;
#pragma unroll
            for (int nt = 0; nt < 4; nt++) { vals[nt] = __expf(vals[nt] - m); s += vals[nt]; }
            s += __shfl_xor(s, 1); s += __shfl_xor(s, 2);
            s += __shfl_xor(s, 4); s += __shfl_xor(s, 8);
            float rinv = 1.f / s;
#pragma unroll
            for (int nt = 0; nt < 4; nt++)
                Pbuf[wv][i * 72 + nt * 16 + c] = f2b(vals[nt] * rinv);
        }
    }

    // ---- O = P V  (64x32, K=64 in 2 steps) ----
    floatx4 accO[4][2] = {};
#pragma unroll
    for (int ks = 0; ks < 2; ks++) {
        short8 pa[4], vb[2];
#pragma unroll
        for (int mt = 0; mt < 4; mt++)
            pa[mt] = *(const short8*)(&Pbuf[wv][(mt * 16 + c) * 72 + ks * 32 + q * 8]);
#pragma unroll
        for (int nt = 0; nt < 2; nt++)
            vb[nt] = *(const short8*)(&Vt[wv][(nt * 16 + c) * 72 + ks * 32 + q * 8]);
#pragma unroll
        for (int mt = 0; mt < 4; mt++)
#pragma unroll
            for (int nt = 0; nt < 2; nt++)
                accO[mt][nt] = __builtin_amdgcn_mfma_f32_16x16x32_bf16(pa[mt], vb[nt], accO[mt][nt], 0, 0, 0);
    }

    // ---- write O (un-roll fold) ----
    int sh = shifted ? 3 : 0;
#pragma unroll
    for (int mt = 0; mt < 4; mt++) {
#pragma unroll
        for (int r = 0; r < 4; r++) {
            int i = mt * 16 + q * 4 + r;
            if (i < 49) {
                int py = i / 7, px = i - py * 7;
                int yo = wy * 7 + py + sh; if (yo >= 56) yo -= 56;
                int xo = wx * 7 + px + sh; if (xo >= 56) xo -= 56;
                long ob = (((long)b * 56 + yo) * 56 + xo) * 256 + h * 32;
                out[ob + c]      = f2b(accO[mt][0][r]);
                out[ob + 16 + c] = f2b(accO[mt][1][r]);
            }
        }
    }
}

// ---------- final LN -> out (dtype per flag) ----------
__global__ __launch_bounds__(256) void k_final(const float* __restrict__ xm,
                                               const void* __restrict__ g,
                                               const void* __restrict__ bb,
                                               void* __restrict__ out,
                                               const int* __restrict__ flagp) {
    const int f = *flagp;
    int t = blockIdx.x, c = threadIdx.x;
    long off = (long)t * 256 + c;
    float v = xm[off];
    __shared__ float red[256];
    red[c] = v; __syncthreads();
#pragma unroll
    for (int s = 128; s > 0; s >>= 1) {
        if (c < s) red[c] += red[c + s];
        __syncthreads();
    }
    float mean = red[0] * (1.f / 256.f);
    __syncthreads();
    float d = v - mean;
    red[c] = d * d; __syncthreads();
#pragma unroll
    for (int s = 128; s > 0; s >>= 1) {
        if (c < s) red[c] += red[c + s];
        __syncthreads();
    }
    float var = red[0] * (1.f / 256.f);
    float ln = d * rsqrtf(var + 1e-5f) * rd(g, c, f) + rd(bb, c, f);
    if (f) ((float*)out)[off] = ln;
    else   ((unsigned short*)out)[off] = f2b(ln);
}

// ---------- launch ----------
extern "C" void kernel_launch(void* const* d_in, const int* in_sizes, int n_in,
                              void* d_out, int out_size, void* d_ws, size_t ws_size,
                              hipStream_t stream) {
    char* ws = (char*)d_ws;
    // fixed region
    float*          xm    = (float*)(ws + 0);                    // 51,380,224 B
    unsigned short* wt    = (unsigned short*)(ws + 51380224);    //  3,145,728 B
    float*          cpb   = (float*)(ws + 54525952);             //    153,664 B
    int*            flagp = (int*)(ws + 54679616);
    const size_t DYN = 54680576;

    // adaptive group count: batches are independent; pick largest Mg that fits ws
    long Mg = NTOK_; int G = 1;
    while (G <= 8) {
        Mg = NTOK_ / G;
        if (DYN + (size_t)Mg * 2560 <= ws_size) break;
        G <<= 1;
    }
    if (G > 8) { G = 8; Mg = NTOK_ / 8; }
    const int NB = 16 / G;
    const bool fused = (G == 1);   // single-group: fuse cast/roll + final LN into epilogues

    unsigned short* xb   = (unsigned short*)(ws + DYN);               // Mg*512 B
    unsigned short* qkvb = (unsigned short*)(ws + DYN + Mg * 512);    // Mg*1536 B
    unsigned short* hid  = (unsigned short*)(ws + DYN + Mg * 512);    // Mg*2048 B (alias qkvb)

    k_detect<<<1, 256, 0, stream>>>((const unsigned short*)d_in[0], flagp);

    for (int l = 0; l < 2; l++) {
        unsigned short* base = wt + (long)l * 786432;
        k_transpose<<<dim3(24, 8), 256, 0, stream>>>(d_in[2],  (long)l * 196608, base,          256, 768,  flagp);
        k_transpose<<<dim3(8, 8),  256, 0, stream>>>(d_in[8],  (long)l * 65536,  base + 196608, 256, 256,  flagp);
        k_transpose<<<dim3(32, 8), 256, 0, stream>>>(d_in[12], (long)l * 262144, base + 262144, 256, 1024, flagp);
        k_transpose<<<dim3(8, 32), 256, 0, stream>>>(d_in[14], (long)l * 262144, base + 524288, 1024, 256, flagp);
    }
    k_cpb<<<dim3(2401, 2), 512, 0, stream>>>(d_in[4], d_in[5], d_in[6], d_in[7], cpb, flagp);
    k_add_spe<<<dim3(12544), 256, 0, stream>>>(d_in[0], d_in[1], xm,
                                               fused ? xb : (unsigned short*)nullptr, flagp);

    for (int l = 0; l < 2; l++) {
        int sh = (l & 1) ? 3 : 0;
        unsigned short* base = wt + (long)l * 786432;
        for (int g = 0; g < G; g++) {
            long m0 = (long)g * Mg;
            if (!fused)
                k_cast_roll<<<dim3(Mg / 4), 256, 0, stream>>>(xm + m0 * 256, xb, sh);
            // qkv = xb @ qkv_w -> bf16   (bn fast + XCD chunk swizzle: A-panel stays on one L2)
            gemm_bt<<<dim3(6, Mg / 128), 256, 0, stream>>>(xb, base, nullptr, 0, qkvb,
                                                           (int)Mg, 768, 256, 4, flagp);
            k_attn<<<dim3(2, 64, NB), 256, 0, stream>>>(qkvb, cpb + (long)l * 19208,
                                                        d_in[3], (long)l * 8, xb, (l & 1), flagp);
            // proj + LN1 + residual (fused); xb refreshed unshifted for fc1
            gemm_ln<<<dim3(Mg / 32), 256, 0, stream>>>(xb, base + 196608, d_in[9], (long)l * 256,
                                                       d_in[10], (long)l * 256, d_in[11], (long)l * 256,
                                                       xm + m0 * 256, xb, 256, 1,
                                                       d_in[18], d_in[19], d_out, flagp);
            // hidden = gelu(xb @ fw1 + fb1) -> bf16
            gemm_bt<<<dim3(8, Mg / 128), 256, 0, stream>>>(xb, base + 262144, d_in[13], (long)l * 1024,
                                                           hid, (int)Mg, 1024, 256, 1 | 2 | 4, flagp);
            // fw2 + LN2 + residual; xb: rolled for next layer (l=0), FUSED FINAL LN (l=1)
            int xbm = fused ? ((l == 0) ? 2 : 3) : 1;
            gemm_ln<<<dim3(Mg / 32), 256, 0, stream>>>(hid, base + 524288, d_in[15], (long)l * 256,
                                                       d_in[16], (long)l * 256, d_in[17], (long)l * 256,
                                                       xm + m0 * 256, xb, 1024, xbm,
                                                       d_in[18], d_in[19], d_out, flagp);
        }
    }
    if (!fused)
        k_final<<<dim3(NTOK_), 256, 0, stream>>>(xm, d_in[18], d_in[19], d_out, flagp);
}